// Round 7
// baseline (547.070 us; speedup 1.0000x reference)
//
#include <hip/hip_runtime.h>
#include <stdint.h>

#define HW 16384
#define CH 384
#define NSPLIT 16

typedef float  f32x4  __attribute__((ext_vector_type(4)));
typedef short  short8 __attribute__((ext_vector_type(8)));
typedef __bf16 bf16x8 __attribute__((ext_vector_type(8)));
typedef unsigned short u16;
typedef u16 u16x4 __attribute__((ext_vector_type(4)));

__device__ __forceinline__ u16 f2bf(float f) {
  union { float f; uint32_t u; } v; v.f = f;
  uint32_t r = v.u + 0x7fffu + ((v.u >> 16) & 1u);
  return (u16)(r >> 16);
}

__device__ __forceinline__ f32x4 zero4() { f32x4 z = {0.f, 0.f, 0.f, 0.f}; return z; }

__device__ __forceinline__ f32x4 mfma_bf16(short8 a, short8 b, f32x4 c) {
  return __builtin_amdgcn_mfma_f32_16x16x32_bf16(
      __builtin_bit_cast(bf16x8, a), __builtin_bit_cast(bf16x8, b), c, 0, 0, 0);
}

// async global->LDS, 16B per lane (dest = wave-uniform base + lane*16)
__device__ __forceinline__ void gload16(const void* g, void* lds) {
  auto gp = (const __attribute__((address_space(1))) uint32_t*)(uintptr_t)g;
  auto lp = (__attribute__((address_space(3))) uint32_t*)(uintptr_t)lds;
  __builtin_amdgcn_global_load_lds(gp, lp, 16, 0, 0);
}

// ---- fp32 -> bf16 weight convert --------------------------------------------
__global__ void k_convert_w(const float* __restrict__ w, u16* __restrict__ o) {
  int i = blockIdx.x * 256 + threadIdx.x;
  if (i < 1152 * CH) o[i] = f2bf(w[i]);
}

// ---- x[b][c][n] fp32 -> xT[b][n][c] bf16; 64x64 tile, f32x4 loads, short8 stores
__global__ __launch_bounds__(256) void k_transpose_x(const float* __restrict__ x,
                                                     u16* __restrict__ xT) {
  __shared__ u16 tile[64][72];  // [n][c], row stride 144B -> uniform bank spread
  const int b = blockIdx.z, c0 = blockIdx.y * 64, n0 = blockIdx.x * 64;
  const int t = threadIdx.x;
  const float* xb = x + (size_t)b * CH * HW;
  const int nq = t & 15;   // n-quad within tile
  const int cr = t >> 4;   // 16 c-rows per pass
#pragma unroll
  for (int jj = 0; jj < 4; ++jj) {
    const int c = cr + jj * 16;
    f32x4 v = *(const f32x4*)(xb + (size_t)(c0 + c) * HW + n0 + nq * 4);
#pragma unroll
    for (int i = 0; i < 4; ++i) tile[nq * 4 + i][c] = f2bf(v[i]);
  }
  __syncthreads();
  u16* xtb = xT + (size_t)b * HW * CH;
  const int cc = t & 7;    // 16B chunk in c
  const int r0 = t >> 3;   // 32 rows per pass
#pragma unroll
  for (int jj = 0; jj < 2; ++jj) {
    const int r = r0 + jj * 32;
    short8 v = *(const short8*)(&tile[r][cc * 8]);
    *(short8*)(xtb + (size_t)(n0 + r) * CH + c0 + cc * 8) = v;
  }
}

// ---- GEMM K32 tile staging into paired-row LDS ------------------------------
// ROWS global rows x 32 u16. LDS: ROWS/2 rows of 128 B; LDS row r holds global
// rows 2r (slots 0-3) and 2r+1 (slots 4-7); physical slot p stores logical
// g8 = p ^ (r & 7). Linear dest (wave base + lane*16, rule 21); swizzle applied
// to the GLOBAL source address. Proven 0-conflict in R5/R6.
template <int ROWS>
__device__ __forceinline__ void stageT(u16* lds, const u16* __restrict__ g, int t) {
  const int w = t >> 6;
#pragma unroll
  for (int s = 0; s < ROWS / 64; ++s) {
    const int r = s * 32 + (t >> 3);
    const int g8 = (t & 7) ^ (r & 7);
    const int gr = 2 * r + (g8 >> 2);
    gload16(g + (size_t)gr * CH + (g8 & 3) * 8, lds + s * 2048 + w * 512);
  }
}

// MODE 0: A=qkv_w_bf16[1152][384], B=xT, out: q,k -> qk[b][o][n] (bf16, in d_out),
//         v -> vT[b][n][o-768] (bf16, ws).  MODE 1: A=M[b][384][384], out fp32.
// Tile 128(o) x 256(n), wave-tile 64x128 (acc 8x4): 12 ds_reads : 32 MFMA per
// K-step. Ring-3 LDS, stage-ahead-2, ONE barrier + counted vmcnt(6) per K-step.
// XCD-chunk swizzle, ot fastest (B-panel L2 reuse).
template <int MODE>
__global__ __launch_bounds__(256, 2) void k_gemm(const u16* __restrict__ Aw,
                                                 const u16* __restrict__ Bx,
                                                 u16* __restrict__ qk,
                                                 u16* __restrict__ vT,
                                                 float* __restrict__ outp) {
  constexpr int NOT = (MODE == 0) ? 9 : 3;      // output-row tiles (of 128)
  constexpr int NWG = NOT * 64 * 4;             // total workgroups (n-tiles of 256)
  constexpr int CHUNK = NWG / 8;                // per-XCD contiguous chunk
  const int orig = blockIdx.x;
  const int L = (orig & 7) * CHUNK + (orig >> 3);  // bijective (NWG % 8 == 0)
  const int ot = L % NOT;
  const int ntg = L / NOT;
  const int b = ntg >> 6;
  const int nt = ntg & 63;

  __shared__ u16 Ws[3][64 * 64];    // 128 rows x 32 k (paired) per slot
  __shared__ u16 Xs[3][128 * 64];   // 256 rows x 32 k (paired) per slot
  const int t = threadIdx.x, lane = t & 63, w = t >> 6;
  const int wo = w & 1, wn = w >> 1;
  const u16* Ab = (MODE == 0 ? Aw : Aw + (size_t)b * CH * CH) + (size_t)ot * 128 * CH;
  const u16* Bb = Bx + (size_t)b * HW * CH + (size_t)nt * 256 * CH;
  const bool swp = (MODE == 0) && (ot >= 6);  // v tiles: swap operands for vT stores

  f32x4 acc[8][4];
#pragma unroll
  for (int i = 0; i < 8; ++i)
#pragma unroll
    for (int j = 0; j < 4; ++j) acc[i][j] = zero4();

  // prologue: tiles 0,1 in flight (6 loads/thread each: 2 W + 4 X)
#pragma unroll
  for (int p = 0; p < 2; ++p) {
    stageT<128>(Ws[p], Ab + p * 32, t);
    stageT<256>(Xs[p], Bb + p * 32, t);
  }

  const int ks = lane >> 4;  // 8-u16 k-chunk 0..3 within the 32-k tile

  for (int kt = 0; kt < 12; ++kt) {
    // retire tile kt's 6 loads (FIFO); keep next tile in flight
    if (kt <= 10) asm volatile("s_waitcnt vmcnt(6)" ::: "memory");
    else          asm volatile("s_waitcnt vmcnt(0)" ::: "memory");
    asm volatile("s_barrier" ::: "memory");  // all waves' tile-kt loads visible
    if (kt <= 9) {  // stage tile kt+2 into slot (kt+2)%3 (readers done at kt-1)
      stageT<128>(Ws[(kt + 2) % 3], Ab + (kt + 2) * 32, t);
      stageT<256>(Xs[(kt + 2) % 3], Bb + (kt + 2) * 32, t);
    }
    const u16* Wc = Ws[kt % 3];
    const u16* Xc = Xs[kt % 3];
    short8 af[4], bfr[8];
#pragma unroll
    for (int mi = 0; mi < 4; ++mi) {
      const int gr = wo * 64 + mi * 16 + (lane & 15);
      const int r = gr >> 1;
      const int p = ((gr & 1) * 4 + ks) ^ (r & 7);
      af[mi] = *(const short8*)(Wc + r * 64 + p * 8);
    }
#pragma unroll
    for (int ni = 0; ni < 8; ++ni) {
      const int gr = wn * 128 + ni * 16 + (lane & 15);
      const int r = gr >> 1;
      const int p = ((gr & 1) * 4 + ks) ^ (r & 7);
      bfr[ni] = *(const short8*)(Xc + r * 64 + p * 8);
    }
    if (!swp) {
#pragma unroll
      for (int ni = 0; ni < 8; ++ni)
#pragma unroll
        for (int mi = 0; mi < 4; ++mi)
          acc[ni][mi] = mfma_bf16(bfr[ni], af[mi], acc[ni][mi]);  // rows=n, cols=o
    } else {
#pragma unroll
      for (int ni = 0; ni < 8; ++ni)
#pragma unroll
        for (int mi = 0; mi < 4; ++mi)
          acc[ni][mi] = mfma_bf16(af[mi], bfr[ni], acc[ni][mi]);  // rows=o, cols=n
    }
  }

  if (MODE == 1) {
    float* ob = outp + (size_t)b * CH * HW;
#pragma unroll
    for (int ni = 0; ni < 8; ++ni)
#pragma unroll
      for (int mi = 0; mi < 4; ++mi) {
        int o = ot * 128 + wo * 64 + mi * 16 + (lane & 15);
        int n = nt * 256 + wn * 128 + ni * 16 + ((lane >> 4) << 2);
        *(f32x4*)(ob + (size_t)o * HW + n) = acc[ni][mi];
      }
  } else if (!swp) {
    u16* qb = qk + (size_t)b * 768 * HW;
#pragma unroll
    for (int ni = 0; ni < 8; ++ni)
#pragma unroll
      for (int mi = 0; mi < 4; ++mi) {
        int o = ot * 128 + wo * 64 + mi * 16 + (lane & 15);
        int n = nt * 256 + wn * 128 + ni * 16 + ((lane >> 4) << 2);
        u16x4 p;
#pragma unroll
        for (int j = 0; j < 4; ++j) p[j] = f2bf(acc[ni][mi][j]);
        *(u16x4*)(qb + (size_t)o * HW + n) = p;
      }
  } else {
    u16* vb = vT + (size_t)b * HW * CH;
#pragma unroll
    for (int ni = 0; ni < 8; ++ni)
#pragma unroll
      for (int mi = 0; mi < 4; ++mi) {
        int o = (ot - 6) * 128 + wo * 64 + mi * 16 + ((lane >> 4) << 2);
        int n = nt * 256 + wn * 128 + ni * 16 + (lane & 15);
        u16x4 p;
#pragma unroll
        for (int j = 0; j < 4; ++j) p[j] = f2bf(acc[ni][mi][j]);
        *(u16x4*)(vb + (size_t)n * CH + o) = p;
      }
  }
}

// ---- Gram: per (b,h,split): S[48][48] += q.k^T over n-chunk; norms via diag(q.q^T)
__global__ __launch_bounds__(256) void k_gram(const u16* __restrict__ qk,
                                              float* __restrict__ part) {
  const int s = blockIdx.x, h = blockIdx.y, b = blockIdx.z;
  const int t = threadIdx.x, lane = t & 63, w = t >> 6;
  const u16* qb = qk + ((size_t)b * 768 + h * 48) * HW;
  const u16* kb = qb + (size_t)CH * HW;
  const int n0 = s * 1024 + w * 256;

  f32x4 S[3][3], Q[3], K2[3];
#pragma unroll
  for (int m = 0; m < 3; ++m) {
    Q[m] = zero4(); K2[m] = zero4();
#pragma unroll
    for (int d = 0; d < 3; ++d) S[m][d] = zero4();
  }
  for (int st = 0; st < 8; ++st) {
    const int n = n0 + st * 32 + ((lane >> 4) << 3);
    short8 qf[3], kf[3];
#pragma unroll
    for (int m = 0; m < 3; ++m)
      qf[m] = *(const short8*)(qb + (size_t)(m * 16 + (lane & 15)) * HW + n);
#pragma unroll
    for (int d = 0; d < 3; ++d)
      kf[d] = *(const short8*)(kb + (size_t)(d * 16 + (lane & 15)) * HW + n);
#pragma unroll
    for (int m = 0; m < 3; ++m) {
      Q[m] = mfma_bf16(qf[m], qf[m], Q[m]);
      K2[m] = mfma_bf16(kf[m], kf[m], K2[m]);
#pragma unroll
      for (int d = 0; d < 3; ++d) S[m][d] = mfma_bf16(qf[m], kf[d], S[m][d]);
    }
  }
  __shared__ float Sw[4][2304];
  __shared__ float Nw[4][96];
#pragma unroll
  for (int m = 0; m < 3; ++m)
#pragma unroll
    for (int d = 0; d < 3; ++d)
#pragma unroll
      for (int j = 0; j < 4; ++j)
        Sw[w][(m * 16 + ((lane >> 4) << 2) + j) * 48 + d * 16 + (lane & 15)] = S[m][d][j];
#pragma unroll
  for (int m = 0; m < 3; ++m)
#pragma unroll
    for (int j = 0; j < 4; ++j)
      if ((((lane >> 4) << 2) + j) == (lane & 15)) {
        Nw[w][m * 16 + (lane & 15)] = Q[m][j];
        Nw[w][48 + m * 16 + (lane & 15)] = K2[m][j];
      }
  __syncthreads();
  float* dst = part + (size_t)((b * 8 + h) * NSPLIT + s) * 2400;
  for (int idx = t; idx < 2304; idx += 256)
    dst[idx] = Sw[0][idx] + Sw[1][idx] + Sw[2][idx] + Sw[3][idx];
  if (t < 96) dst[2304 + t] = Nw[0][t] + Nw[1][t] + Nw[2][t] + Nw[3][t];
}

// ---- softmax + M = proj_w(block) @ attn  (per b,h) --------------------------
__global__ __launch_bounds__(384) void k_softmax_M(const float* __restrict__ part,
                                                   const float* __restrict__ projw,
                                                   const float* __restrict__ temp,
                                                   u16* __restrict__ Mbf) {
  const int h = blockIdx.x, b = blockIdx.y;
  const int t = threadIdx.x;
  __shared__ float S[2304];
  __shared__ float attn[48][48];
  __shared__ float nrm[96];
  const float* p = part + (size_t)(b * 8 + h) * NSPLIT * 2400;
  for (int idx = t; idx < 2304; idx += 384) {
    float a = 0.f;
#pragma unroll
    for (int s = 0; s < NSPLIT; ++s) a += p[(size_t)s * 2400 + idx];
    S[idx] = a;
  }
  if (t < 96) {
    float a = 0.f;
#pragma unroll
    for (int s = 0; s < NSPLIT; ++s) a += p[(size_t)s * 2400 + 2304 + t];
    nrm[t] = a;
  }
  __syncthreads();
  if (t < 48) {
    const float th = temp[h];
    const float inq = 1.f / fmaxf(sqrtf(nrm[t]), 1e-12f);
    float l[48];
    float mx = -3.4e38f;
#pragma unroll
    for (int d = 0; d < 48; ++d) {
      float ik = 1.f / fmaxf(sqrtf(nrm[48 + d]), 1e-12f);
      float lg = S[t * 48 + d] * inq * ik * th;
      l[d] = lg;
      mx = fmaxf(mx, lg);
    }
    float sum = 0.f;
#pragma unroll
    for (int d = 0; d < 48; ++d) { float e = __expf(l[d] - mx); l[d] = e; sum += e; }
    float inv = 1.f / sum;
#pragma unroll
    for (int d = 0; d < 48; ++d) attn[t][d] = l[d] * inv;
  }
  __syncthreads();
  const int o = t;
  float pw[48];
#pragma unroll
  for (int c = 0; c < 48; ++c) pw[c] = projw[(size_t)o * CH + h * 48 + c];
  u16* Mb = Mbf + ((size_t)b * CH + o) * CH + h * 48;
#pragma unroll 4
  for (int d = 0; d < 48; ++d) {
    float a = 0.f;
#pragma unroll
    for (int c = 0; c < 48; ++c) a = fmaf(pw[c], attn[c][d], a);
    Mb[d] = f2bf(a);
  }
}

extern "C" void kernel_launch(void* const* d_in, const int* in_sizes, int n_in,
                              void* d_out, int out_size, void* d_ws, size_t ws_size,
                              hipStream_t stream) {
  const float* x     = (const float*)d_in[0];
  const float* qkvw  = (const float*)d_in[1];
  const float* projw = (const float*)d_in[2];
  const float* temp  = (const float*)d_in[3];
  float* out = (float*)d_out;
  char* ws = (char*)d_ws;

  // ws layout (bytes)
  u16*   xT   = (u16*)(ws);                      // 4*16384*384*2 = 50331648
  u16*   vT   = (u16*)(ws + 50331648);           // 50331648
  u16*   wbf  = (u16*)(ws + 100663296);          // 1152*384*2 = 884736
  u16*   Mbf  = (u16*)(ws + 101548032);          // 4*384*384*2 = 1179648
  float* part = (float*)(ws + 102727680);        // 512*2400*4 = 4915200
  u16*   qkbuf = (u16*)d_out;                    // q,k bf16 live in d_out until GEMM2

  k_convert_w<<<dim3((1152 * CH + 255) / 256), 256, 0, stream>>>(qkvw, wbf);
  k_transpose_x<<<dim3(HW / 64, CH / 64, 4), 256, 0, stream>>>(x, xT);
  k_gemm<0><<<dim3(9 * 64 * 4), 256, 0, stream>>>(wbf, xT, qkbuf, vT, nullptr);
  k_gram<<<dim3(NSPLIT, 8, 4), 256, 0, stream>>>(qkbuf, part);
  k_softmax_M<<<dim3(8, 4), 384, 0, stream>>>(part, projw, temp, Mbf);
  k_gemm<1><<<dim3(3 * 64 * 4), 256, 0, stream>>>(Mbf, vT, nullptr, nullptr, out);
}

// Round 8
// 189.420 us; speedup vs baseline: 2.8881x; 2.8881x over previous
//
#include <hip/hip_runtime.h>
#include <stdint.h>

#define HW 16384
#define CH 384
#define NS 16

typedef float  f32x4  __attribute__((ext_vector_type(4)));
typedef short  short8 __attribute__((ext_vector_type(8)));
typedef __bf16 bf16x8 __attribute__((ext_vector_type(8)));
typedef unsigned short u16;
typedef u16 u16x4 __attribute__((ext_vector_type(4)));

__device__ __forceinline__ u16 f2bf(float f) {
  union { float f; uint32_t u; } v; v.f = f;
  uint32_t r = v.u + 0x7fffu + ((v.u >> 16) & 1u);
  return (u16)(r >> 16);
}
__device__ __forceinline__ float bf2f(u16 v) {
  union { uint32_t u; float f; } x; x.u = ((uint32_t)v) << 16; return x.f;
}
__device__ __forceinline__ f32x4 zero4() { f32x4 z = {0.f, 0.f, 0.f, 0.f}; return z; }

__device__ __forceinline__ f32x4 mfma_bf16(short8 a, short8 b, f32x4 c) {
  return __builtin_amdgcn_mfma_f32_16x16x32_bf16(
      __builtin_bit_cast(bf16x8, a), __builtin_bit_cast(bf16x8, b), c, 0, 0, 0);
}

__device__ __forceinline__ void gload16(const void* g, void* lds) {
  auto gp = (const __attribute__((address_space(1))) uint32_t*)(uintptr_t)g;
  auto lp = (__attribute__((address_space(3))) uint32_t*)(uintptr_t)lds;
  __builtin_amdgcn_global_load_lds(gp, lp, 16, 0, 0);
}

// ---- fp32 -> bf16 weight convert --------------------------------------------
__global__ void k_convert_w(const float* __restrict__ w, u16* __restrict__ o) {
  int i = blockIdx.x * 256 + threadIdx.x;
  if (i < 1152 * CH) o[i] = f2bf(w[i]);
}

// ---- WvT[c][d] = qkv_w[768+d][c] bf16 (384x384 transpose) -------------------
__global__ __launch_bounds__(256) void k_wvt(const float* __restrict__ w,
                                             u16* __restrict__ wvt) {
  __shared__ u16 tl[64][72];
  const int ci = blockIdx.x, di = blockIdx.y, t = threadIdx.x;
#pragma unroll
  for (int jj = 0; jj < 4; ++jj) {
    const int r = (t >> 4) + jj * 16;
    f32x4 v = *(const f32x4*)(w + (size_t)(768 + di * 64 + r) * CH + ci * 64 + (t & 15) * 4);
#pragma unroll
    for (int i = 0; i < 4; ++i) tl[(t & 15) * 4 + i][r] = f2bf(v[i]);
  }
  __syncthreads();
#pragma unroll
  for (int jj = 0; jj < 2; ++jj) {
    const int c = (t >> 3) + jj * 32;
    short8 v = *(const short8*)(&tl[c][(t & 7) * 8]);
    *(short8*)(wvt + (size_t)(ci * 64 + c) * CH + di * 64 + (t & 7) * 8) = v;
  }
}

// ---- x[b][c][n] fp32 -> xT[b][n][c] bf16 AND xb[b][c][n] bf16 ---------------
__global__ __launch_bounds__(256) void k_transpose_x(const float* __restrict__ x,
                                                     u16* __restrict__ xT,
                                                     u16* __restrict__ xb) {
  __shared__ u16 tile[64][72];
  const int b = blockIdx.z, c0 = blockIdx.y * 64, n0 = blockIdx.x * 64;
  const int t = threadIdx.x;
  const float* xp = x + (size_t)b * CH * HW;
  u16* xbp = xb + (size_t)b * CH * HW;
  const int nq = t & 15;
  const int cr = t >> 4;
#pragma unroll
  for (int jj = 0; jj < 4; ++jj) {
    const int c = cr + jj * 16;
    f32x4 v = *(const f32x4*)(xp + (size_t)(c0 + c) * HW + n0 + nq * 4);
    u16x4 pk;
#pragma unroll
    for (int i = 0; i < 4; ++i) { u16 bv = f2bf(v[i]); tile[nq * 4 + i][c] = bv; pk[i] = bv; }
    *(u16x4*)(xbp + (size_t)(c0 + c) * HW + n0 + nq * 4) = pk;
  }
  __syncthreads();
  u16* xtb = xT + (size_t)b * HW * CH;
  const int cc = t & 7;
  const int r0 = t >> 3;
#pragma unroll
  for (int jj = 0; jj < 2; ++jj) {
    const int r = r0 + jj * 32;
    short8 v = *(const short8*)(&tile[r][cc * 8]);
    *(short8*)(xtb + (size_t)(n0 + r) * CH + c0 + cc * 8) = v;
  }
}

// ---- gram of x: G-tile partials. pair p -> panels (i,j) ---------------------
// part[(b*6+pair)*NS+ns][ai][bj] f32 (128x128 tile, ai = i-panel row)
__global__ __launch_bounds__(256) void k_gramx(const u16* __restrict__ xb,
                                               float* __restrict__ part) {
  const int orig = blockIdx.x;                 // 6*NS*4 = 384, %8==0
  const int L = (orig & 7) * 48 + (orig >> 3); // bijective XCD chunk
  const int pair = L % 6;
  const int ns = (L / 6) % NS;
  const int b = L / (6 * NS);
  const int i = pair < 3 ? 0 : (pair < 5 ? 1 : 2);
  const int j = pair < 3 ? pair : (pair < 5 ? pair - 2 : 2);
  const int t = threadIdx.x, lane = t & 63, w = t >> 6;
  const int wo = w & 1, wn = w >> 1;
  const u16* pa = xb + ((size_t)b * CH + i * 128) * HW;
  const u16* pb = xb + ((size_t)b * CH + j * 128) * HW;

  f32x4 acc[4][4];
#pragma unroll
  for (int a = 0; a < 4; ++a)
#pragma unroll
    for (int c = 0; c < 4; ++c) acc[a][c] = zero4();

  for (int st = 0; st < 32; ++st) {
    const int n = ns * 1024 + st * 32 + ((lane >> 4) << 3);
    short8 af[4], bf[4];
#pragma unroll
    for (int mi = 0; mi < 4; ++mi)
      af[mi] = *(const short8*)(pa + (size_t)(wo * 64 + mi * 16 + (lane & 15)) * HW + n);
#pragma unroll
    for (int ni = 0; ni < 4; ++ni)
      bf[ni] = *(const short8*)(pb + (size_t)(wn * 64 + ni * 16 + (lane & 15)) * HW + n);
#pragma unroll
    for (int ni = 0; ni < 4; ++ni)
#pragma unroll
      for (int mi = 0; mi < 4; ++mi)
        acc[ni][mi] = mfma_bf16(bf[ni], af[mi], acc[ni][mi]);
  }
  float* dst = part + ((size_t)(b * 6 + pair) * NS + ns) * 16384;
#pragma unroll
  for (int ni = 0; ni < 4; ++ni)
#pragma unroll
    for (int mi = 0; mi < 4; ++mi) {
      const int ai = wo * 64 + mi * 16 + (lane & 15);
      const int bj = wn * 64 + ni * 16 + ((lane >> 4) << 2);
      *(f32x4*)(dst + (size_t)ai * 128 + bj) = acc[ni][mi];
    }
}

// ---- reduce partials -> Goff bf16 (diag zeroed, mirrored) + Gd f32 ----------
__global__ __launch_bounds__(256) void k_greduce(const float* __restrict__ part,
                                                 u16* __restrict__ Goff,
                                                 float* __restrict__ Gd) {
  const int cq = blockIdx.x, pair = blockIdx.y, b = blockIdx.z;
  const int i = pair < 3 ? 0 : (pair < 5 ? 1 : 2);
  const int j = pair < 3 ? pair : (pair < 5 ? pair - 2 : 2);
  const int t = threadIdx.x;
  const int c0 = cq * 32;
  __shared__ u16 tl[32][136];
  const float* src = part + (size_t)(b * 6 + pair) * NS * 16384;
#pragma unroll
  for (int p = 0; p < 4; ++p) {
    const int q = t + p * 256;
    const int ai = q >> 3;
    const int bj = c0 + (q & 7) * 4;
    f32x4 s = zero4();
    for (int ns = 0; ns < NS; ++ns) s += *(const f32x4*)(src + (size_t)ns * 16384 + ai * 128 + bj);
    if (i == j) {
#pragma unroll
      for (int jj = 0; jj < 4; ++jj)
        if (ai == bj + jj) { Gd[b * CH + i * 128 + ai] = s[jj]; s[jj] = 0.f; }
    }
    u16x4 pk;
#pragma unroll
    for (int jj = 0; jj < 4; ++jj) { pk[jj] = f2bf(s[jj]); tl[bj - c0 + jj][ai] = pk[jj]; }
    *(u16x4*)(Goff + ((size_t)b * CH + i * 128 + ai) * CH + j * 128 + bj) = pk;
  }
  if (i != j) {
    __syncthreads();
#pragma unroll
    for (int jj = 0; jj < 2; ++jj) {
      const int r = t >> 3;
      const int ch = ((t & 7) + jj * 8) * 8;
      short8 v = *(const short8*)(&tl[r][ch]);
      *(short8*)(Goff + ((size_t)b * CH + j * 128 + c0 + r) * CH + i * 128 + ch) = v;
    }
  }
}

// ---- stage 128 rows x 32 k, paired-row LDS, proven 0-conflict (R5/R6) -------
__device__ __forceinline__ void stage32p(u16* lds, const u16* __restrict__ g, int t) {
  const int w = t >> 6;
#pragma unroll
  for (int s = 0; s < 2; ++s) {
    const int r = s * 32 + (t >> 3);
    const int g8 = (t & 7) ^ (r & 7);
    const int gr = 2 * r + (g8 >> 2);
    gload16(g + (size_t)gr * CH + (g8 & 3) * 8, lds + s * 2048 + w * 512);
  }
}

// ---- mini GEMM 128x128, K=384: C = A x B^T (B rows k-contig), ring-4 --------
// TM=1: T = Wqk*Goff + diagfix (f32 out).  TM=0: P = M*WvT (bf16 out).
template <int TM>
__global__ __launch_bounds__(256) void k_mini(const u16* __restrict__ A,
                                              const u16* __restrict__ B,
                                              float* __restrict__ Tout,
                                              u16* __restrict__ Bout,
                                              const float* __restrict__ Gd,
                                              const u16* __restrict__ Wd) {
  const int nt = blockIdx.x, mt = blockIdx.y, b = blockIdx.z;
  __shared__ u16 Ws[4][64 * 64];
  __shared__ u16 Xs[4][64 * 64];
  const int t = threadIdx.x, lane = t & 63, w = t >> 6;
  const int wo = w & 1, wn = w >> 1;
  const u16* Ab = A + (TM ? 0 : (size_t)b * CH * CH) + (size_t)mt * 128 * CH;
  const u16* Bb = B + (TM ? (size_t)b * CH * CH : 0) + (size_t)nt * 128 * CH;

  f32x4 acc[4][4];
#pragma unroll
  for (int a = 0; a < 4; ++a)
#pragma unroll
    for (int c = 0; c < 4; ++c) acc[a][c] = zero4();

#pragma unroll
  for (int p = 0; p < 3; ++p) {
    stage32p(Ws[p], Ab + p * 32, t);
    stage32p(Xs[p], Bb + p * 32, t);
  }
  const int ks = lane >> 4;
  for (int kt = 0; kt < 12; ++kt) {
    if (kt <= 9)       asm volatile("s_waitcnt vmcnt(8)" ::: "memory");
    else if (kt == 10) asm volatile("s_waitcnt vmcnt(4)" ::: "memory");
    else               asm volatile("s_waitcnt vmcnt(0)" ::: "memory");
    asm volatile("s_barrier" ::: "memory");
    if (kt < 9) {
      stage32p(Ws[(kt + 3) & 3], Ab + (kt + 3) * 32, t);
      stage32p(Xs[(kt + 3) & 3], Bb + (kt + 3) * 32, t);
    }
    const u16* Wc = Ws[kt & 3];
    const u16* Xc = Xs[kt & 3];
    short8 af[4], bfr[4];
#pragma unroll
    for (int mi = 0; mi < 4; ++mi) {
      const int gr = wo * 64 + mi * 16 + (lane & 15);
      const int r = gr >> 1;
      const int p = ((gr & 1) * 4 + ks) ^ (r & 7);
      af[mi] = *(const short8*)(Wc + r * 64 + p * 8);
    }
#pragma unroll
    for (int ni = 0; ni < 4; ++ni) {
      const int gr = wn * 64 + ni * 16 + (lane & 15);
      const int r = gr >> 1;
      const int p = ((gr & 1) * 4 + ks) ^ (r & 7);
      bfr[ni] = *(const short8*)(Xc + r * 64 + p * 8);
    }
#pragma unroll
    for (int ni = 0; ni < 4; ++ni)
#pragma unroll
      for (int mi = 0; mi < 4; ++mi)
        acc[ni][mi] = mfma_bf16(bfr[ni], af[mi], acc[ni][mi]);
  }

#pragma unroll
  for (int ni = 0; ni < 4; ++ni)
#pragma unroll
    for (int mi = 0; mi < 4; ++mi) {
      const int tr = mt * 128 + wo * 64 + mi * 16 + (lane & 15);   // A-row (C col)
      const int d0 = nt * 128 + wn * 64 + ni * 16 + ((lane >> 4) << 2);  // B-row
      if (TM) {
        f32x4 g = *(const f32x4*)(Gd + b * CH + d0);
        u16x4 w4 = *(const u16x4*)(Wd + (size_t)tr * CH + d0);
        f32x4 v;
#pragma unroll
        for (int jj = 0; jj < 4; ++jj) v[jj] = acc[ni][mi][jj] + bf2f(w4[jj]) * g[jj];
        *(f32x4*)(Tout + ((size_t)b * 768 + tr) * CH + d0) = v;
      } else {
        u16x4 pk;
#pragma unroll
        for (int jj = 0; jj < 4; ++jj) pk[jj] = f2bf(acc[ni][mi][jj]);
        *(u16x4*)(Bout + ((size_t)b * CH + tr) * CH + d0) = pk;
      }
    }
}

// ---- per (b,h): S = T1*Wk^T (MFMA, wave0) ; norms ; softmax ; M = proj∘attn -
__global__ __launch_bounds__(384) void k_attn(const float* __restrict__ T,
                                              const u16* __restrict__ wbf,
                                              const float* __restrict__ projw,
                                              const float* __restrict__ temp,
                                              u16* __restrict__ Mbf) {
  const int h = blockIdx.x, b = blockIdx.y, t = threadIdx.x;
  __shared__ float Sl[48][48];
  __shared__ float attn[48][48];
  __shared__ float nrm[96];
  const float* T1 = T + ((size_t)b * 768 + h * 48) * CH;
  const float* T2 = T1 + (size_t)384 * CH;
  const u16* wk = wbf + (size_t)(384 + h * 48) * CH;

  if (t < 64) {  // wave 0: S[48][48] via MFMA, K=384
    const int lane = t;
    f32x4 sa[3][3];
#pragma unroll
    for (int a = 0; a < 3; ++a)
#pragma unroll
      for (int c = 0; c < 3; ++c) sa[a][c] = zero4();
    for (int kk = 0; kk < 12; ++kk) {
      const int kc = kk * 32 + ((lane >> 4) << 3);
      short8 afr[3], bfr[3];
#pragma unroll
      for (int mi = 0; mi < 3; ++mi) {
        const float* s = T1 + (size_t)(mi * 16 + (lane & 15)) * CH + kc;
        f32x4 v0 = *(const f32x4*)(s);
        f32x4 v1 = *(const f32x4*)(s + 4);
        short8 a;
#pragma unroll
        for (int jj = 0; jj < 4; ++jj) { a[jj] = (short)f2bf(v0[jj]); a[4 + jj] = (short)f2bf(v1[jj]); }
        afr[mi] = a;
      }
#pragma unroll
      for (int ni = 0; ni < 3; ++ni)
        bfr[ni] = *(const short8*)(wk + (size_t)(ni * 16 + (lane & 15)) * CH + kc);
#pragma unroll
      for (int ni = 0; ni < 3; ++ni)
#pragma unroll
        for (int mi = 0; mi < 3; ++mi)
          sa[ni][mi] = mfma_bf16(bfr[ni], afr[mi], sa[ni][mi]);
    }
#pragma unroll
    for (int ni = 0; ni < 3; ++ni)
#pragma unroll
      for (int mi = 0; mi < 3; ++mi)
#pragma unroll
        for (int jj = 0; jj < 4; ++jj)
          Sl[mi * 16 + (lane & 15)][ni * 16 + ((lane >> 4) << 2) + jj] = sa[ni][mi][jj];
  } else if (t < 160) {  // norms
    const int r = t - 64;
    const float* Tr = (r < 48) ? T1 + (size_t)r * CH : T2 + (size_t)(r - 48) * CH;
    const u16* wr = (r < 48) ? wbf + (size_t)(h * 48 + r) * CH
                             : wbf + (size_t)(384 + h * 48 + (r - 48)) * CH;
    float a = 0.f;
    for (int c = 0; c < 384; ++c) a += Tr[c] * bf2f(wr[c]);
    nrm[r] = a;
  }
  __syncthreads();
  if (t < 48) {
    const float th = temp[h];
    const float inq = 1.f / fmaxf(sqrtf(nrm[t]), 1e-12f);
    float l[48];
    float mx = -3.4e38f;
#pragma unroll
    for (int u = 0; u < 48; ++u) {
      float ik = 1.f / fmaxf(sqrtf(nrm[48 + u]), 1e-12f);
      float lg = Sl[t][u] * inq * ik * th;
      l[u] = lg;
      mx = fmaxf(mx, lg);
    }
    float sum = 0.f;
#pragma unroll
    for (int u = 0; u < 48; ++u) { float e = __expf(l[u] - mx); l[u] = e; sum += e; }
    float inv = 1.f / sum;
#pragma unroll
    for (int u = 0; u < 48; ++u) attn[t][u] = l[u] * inv;
  }
  __syncthreads();
  float pw[48];
#pragma unroll
  for (int c = 0; c < 48; ++c) pw[c] = projw[(size_t)t * CH + h * 48 + c];
  u16* Mb = Mbf + ((size_t)b * CH + t) * CH + h * 48;
#pragma unroll 4
  for (int d = 0; d < 48; ++d) {
    float a = 0.f;
#pragma unroll
    for (int c = 0; c < 48; ++c) a = fmaf(pw[c], attn[c][d], a);
    Mb[d] = f2bf(a);
  }
}

// ---- final: out[b] = P_b * xT  (R6 MODE-1 clone, ring-4, XCD swizzle) -------
__global__ __launch_bounds__(256) void k_final(const u16* __restrict__ P,
                                               const u16* __restrict__ Bx,
                                               float* __restrict__ outp) {
  constexpr int NWG = 3 * 128 * 4;
  constexpr int CHUNK = NWG / 8;
  const int orig = blockIdx.x;
  const int L = (orig & 7) * CHUNK + (orig >> 3);
  const int ot = L % 3;
  const int ntg = L / 3;
  const int b = ntg >> 7;
  const int nt = ntg & 127;

  __shared__ u16 Ws[4][64 * 64];
  __shared__ u16 Xs[4][64 * 64];
  const int t = threadIdx.x, lane = t & 63, w = t >> 6;
  const int wo = w & 1, wn = w >> 1;
  const u16* Ab = P + (size_t)b * CH * CH + (size_t)ot * 128 * CH;
  const u16* Bb = Bx + (size_t)b * HW * CH + (size_t)nt * 128 * CH;

  f32x4 acc[4][4];
#pragma unroll
  for (int a = 0; a < 4; ++a)
#pragma unroll
    for (int c = 0; c < 4; ++c) acc[a][c] = zero4();

#pragma unroll
  for (int p = 0; p < 3; ++p) {
    stage32p(Ws[p], Ab + p * 32, t);
    stage32p(Xs[p], Bb + p * 32, t);
  }
  const int ks = lane >> 4;
  for (int kt = 0; kt < 12; ++kt) {
    if (kt <= 9)       asm volatile("s_waitcnt vmcnt(8)" ::: "memory");
    else if (kt == 10) asm volatile("s_waitcnt vmcnt(4)" ::: "memory");
    else               asm volatile("s_waitcnt vmcnt(0)" ::: "memory");
    asm volatile("s_barrier" ::: "memory");
    if (kt < 9) {
      stage32p(Ws[(kt + 3) & 3], Ab + (kt + 3) * 32, t);
      stage32p(Xs[(kt + 3) & 3], Bb + (kt + 3) * 32, t);
    }
    const u16* Wc = Ws[kt & 3];
    const u16* Xc = Xs[kt & 3];
    short8 af[4], bfr[4];
#pragma unroll
    for (int mi = 0; mi < 4; ++mi) {
      const int gr = wo * 64 + mi * 16 + (lane & 15);
      const int r = gr >> 1;
      const int p = ((gr & 1) * 4 + ks) ^ (r & 7);
      af[mi] = *(const short8*)(Wc + r * 64 + p * 8);
    }
#pragma unroll
    for (int ni = 0; ni < 4; ++ni) {
      const int gr = wn * 64 + ni * 16 + (lane & 15);
      const int r = gr >> 1;
      const int p = ((gr & 1) * 4 + ks) ^ (r & 7);
      bfr[ni] = *(const short8*)(Xc + r * 64 + p * 8);
    }
#pragma unroll
    for (int ni = 0; ni < 4; ++ni)
#pragma unroll
      for (int mi = 0; mi < 4; ++mi)
        acc[ni][mi] = mfma_bf16(bfr[ni], af[mi], acc[ni][mi]);
  }
  float* ob = outp + (size_t)b * CH * HW;
#pragma unroll
  for (int ni = 0; ni < 4; ++ni)
#pragma unroll
    for (int mi = 0; mi < 4; ++mi) {
      int o = ot * 128 + wo * 64 + mi * 16 + (lane & 15);
      int n = nt * 128 + wn * 64 + ni * 16 + ((lane >> 4) << 2);
      *(f32x4*)(ob + (size_t)o * HW + n) = acc[ni][mi];
    }
}

extern "C" void kernel_launch(void* const* d_in, const int* in_sizes, int n_in,
                              void* d_out, int out_size, void* d_ws, size_t ws_size,
                              hipStream_t stream) {
  const float* x     = (const float*)d_in[0];
  const float* qkvw  = (const float*)d_in[1];
  const float* projw = (const float*)d_in[2];
  const float* temp  = (const float*)d_in[3];
  float* out = (float*)d_out;
  char* ws = (char*)d_ws;

  // ws layout
  u16*   xT   = (u16*)(ws);                      // 50,331,648
  u16*   wbf  = (u16*)(ws + 50331648);           // 884,736
  u16*   wvt  = (u16*)(ws + 51216384);           // 294,912
  u16*   Goff = (u16*)(ws + 51511296);           // 1,179,648
  float* Gd   = (float*)(ws + 52690944);         // 6,144
  float* Tf   = (float*)(ws + 52697088);         // 4,718,592
  u16*   Mbf  = (u16*)(ws + 57415680);           // 1,179,648
  u16*   Pbf  = (u16*)(ws + 58595328);           // 1,179,648
  // d_out scratch (overwritten by k_final): xb bf16 + gram partials
  u16*   xb   = (u16*)d_out;                     // 50,331,648
  float* part = (float*)((char*)d_out + 50331648);  // 6*NS*16384*4*4b = 25,165,824

  k_convert_w<<<dim3((1152 * CH + 255) / 256), 256, 0, stream>>>(qkvw, wbf);
  k_wvt<<<dim3(6, 6), 256, 0, stream>>>(qkvw, wvt);
  k_transpose_x<<<dim3(HW / 64, CH / 64, 4), 256, 0, stream>>>(x, xT, xb);
  k_gramx<<<dim3(6 * NS * 4), 256, 0, stream>>>(xb, part);
  k_greduce<<<dim3(4, 6, 4), 256, 0, stream>>>(part, Goff, Gd);
  k_mini<1><<<dim3(3, 6, 4), 256, 0, stream>>>(wbf, Goff, Tf, nullptr, Gd, wbf);
  k_attn<<<dim3(8, 4), 384, 0, stream>>>(Tf, wbf, projw, temp, Mbf);
  k_mini<0><<<dim3(3, 3, 4), 256, 0, stream>>>(Mbf, wvt, nullptr, Pbf, nullptr, nullptr);
  k_final<<<dim3(3 * 128 * 4), 256, 0, stream>>>(Pbf, xT, out);
}

// Round 9
// 156.468 us; speedup vs baseline: 3.4964x; 1.2106x over previous
//
#include <hip/hip_runtime.h>
#include <stdint.h>

#define HW 16384
#define CH 384
#define NS 32

typedef float  f32x4  __attribute__((ext_vector_type(4)));
typedef short  short8 __attribute__((ext_vector_type(8)));
typedef __bf16 bf16x8 __attribute__((ext_vector_type(8)));
typedef unsigned short u16;
typedef u16 u16x4 __attribute__((ext_vector_type(4)));

__device__ __forceinline__ u16 f2bf(float f) {
  union { float f; uint32_t u; } v; v.f = f;
  uint32_t r = v.u + 0x7fffu + ((v.u >> 16) & 1u);
  return (u16)(r >> 16);
}
__device__ __forceinline__ float bf2f(u16 v) {
  union { uint32_t u; float f; } x; x.u = ((uint32_t)v) << 16; return x.f;
}
__device__ __forceinline__ f32x4 zero4() { f32x4 z = {0.f, 0.f, 0.f, 0.f}; return z; }

__device__ __forceinline__ f32x4 mfma_bf16(short8 a, short8 b, f32x4 c) {
  return __builtin_amdgcn_mfma_f32_16x16x32_bf16(
      __builtin_bit_cast(bf16x8, a), __builtin_bit_cast(bf16x8, b), c, 0, 0, 0);
}

__device__ __forceinline__ void gload16(const void* g, void* lds) {
  auto gp = (const __attribute__((address_space(1))) uint32_t*)(uintptr_t)g;
  auto lp = (__attribute__((address_space(3))) uint32_t*)(uintptr_t)lds;
  __builtin_amdgcn_global_load_lds(gp, lp, 16, 0, 0);
}

// ---- fp32 -> bf16 weight convert --------------------------------------------
__global__ void k_convert_w(const float* __restrict__ w, u16* __restrict__ o) {
  int i = blockIdx.x * 256 + threadIdx.x;
  if (i < 1152 * CH) o[i] = f2bf(w[i]);
}

// ---- WvT[c][d] = qkv_w[768+d][c] bf16 (384x384 transpose) -------------------
__global__ __launch_bounds__(256) void k_wvt(const float* __restrict__ w,
                                             u16* __restrict__ wvt) {
  __shared__ u16 tl[64][72];
  const int ci = blockIdx.x, di = blockIdx.y, t = threadIdx.x;
#pragma unroll
  for (int jj = 0; jj < 4; ++jj) {
    const int r = (t >> 4) + jj * 16;
    f32x4 v = *(const f32x4*)(w + (size_t)(768 + di * 64 + r) * CH + ci * 64 + (t & 15) * 4);
#pragma unroll
    for (int i = 0; i < 4; ++i) tl[(t & 15) * 4 + i][r] = f2bf(v[i]);
  }
  __syncthreads();
#pragma unroll
  for (int jj = 0; jj < 2; ++jj) {
    const int c = (t >> 3) + jj * 32;
    short8 v = *(const short8*)(&tl[c][(t & 7) * 8]);
    *(short8*)(wvt + (size_t)(ci * 64 + c) * CH + di * 64 + (t & 7) * 8) = v;
  }
}

// ---- x[b][c][n] fp32 -> xT[b][n][c] bf16 AND xb[b][c][n] bf16 ---------------
__global__ __launch_bounds__(256) void k_transpose_x(const float* __restrict__ x,
                                                     u16* __restrict__ xT,
                                                     u16* __restrict__ xb) {
  __shared__ u16 tile[64][72];
  const int b = blockIdx.z, c0 = blockIdx.y * 64, n0 = blockIdx.x * 64;
  const int t = threadIdx.x;
  const float* xp = x + (size_t)b * CH * HW;
  u16* xbp = xb + (size_t)b * CH * HW;
  const int nq = t & 15;
  const int cr = t >> 4;
#pragma unroll
  for (int jj = 0; jj < 4; ++jj) {
    const int c = cr + jj * 16;
    f32x4 v = *(const f32x4*)(xp + (size_t)(c0 + c) * HW + n0 + nq * 4);
    u16x4 pk;
#pragma unroll
    for (int i = 0; i < 4; ++i) { u16 bv = f2bf(v[i]); tile[nq * 4 + i][c] = bv; pk[i] = bv; }
    *(u16x4*)(xbp + (size_t)(c0 + c) * HW + n0 + nq * 4) = pk;
  }
  __syncthreads();
  u16* xtb = xT + (size_t)b * HW * CH;
  const int cc = t & 7;
  const int r0 = t >> 3;
#pragma unroll
  for (int jj = 0; jj < 2; ++jj) {
    const int r = r0 + jj * 32;
    short8 v = *(const short8*)(&tile[r][cc * 8]);
    *(short8*)(xtb + (size_t)(n0 + r) * CH + c0 + cc * 8) = v;
  }
}

// ---- stage 128 rows x 32 k, paired-row LDS, proven 0-conflict (R5/R6) -------
// Row stride templated: CH for 384-wide matrices, HW for x panels.
template <int STRIDE>
__device__ __forceinline__ void stageS(u16* lds, const u16* __restrict__ g, int t) {
  const int w = t >> 6;
#pragma unroll
  for (int s = 0; s < 2; ++s) {
    const int r = s * 32 + (t >> 3);
    const int g8 = (t & 7) ^ (r & 7);
    const int gr = 2 * r + (g8 >> 2);
    gload16(g + (size_t)gr * STRIDE + (g8 & 3) * 8, lds + s * 2048 + w * 512);
  }
}

// ---- gram of x: G-tile partials via staged ring-3 pipeline ------------------
// part[(b*6+pair)*NS+ns][ai][bj] f32 (128x128 tile); per block: K-range 512.
__global__ __launch_bounds__(256) void k_gramx(const u16* __restrict__ xb,
                                               float* __restrict__ part) {
  const int orig = blockIdx.x;                  // 6*NS*4 = 768, %8==0
  const int L = (orig & 7) * (6 * NS * 4 / 8) + (orig >> 3);  // bijective XCD chunk
  const int pair = L % 6;
  const int ns = (L / 6) % NS;
  const int b = L / (6 * NS);
  const int i = pair < 3 ? 0 : (pair < 5 ? 1 : 2);
  const int j = pair < 3 ? pair : (pair < 5 ? pair - 2 : 2);
  const int t = threadIdx.x, lane = t & 63, w = t >> 6;
  const int wo = w & 1, wn = w >> 1;
  const u16* pa = xb + ((size_t)b * CH + i * 128) * HW + ns * 512;
  const u16* pb = xb + ((size_t)b * CH + j * 128) * HW + ns * 512;

  __shared__ u16 As[3][64 * 64];
  __shared__ u16 Bs[3][64 * 64];

  f32x4 acc[4][4];
#pragma unroll
  for (int a = 0; a < 4; ++a)
#pragma unroll
    for (int c = 0; c < 4; ++c) acc[a][c] = zero4();

  // prologue: tiles 0,1 (4 loads/thread each: 2 A + 2 B)
#pragma unroll
  for (int p = 0; p < 2; ++p) {
    stageS<HW>(As[p], pa + p * 32, t);
    stageS<HW>(Bs[p], pb + p * 32, t);
  }
  const int ks = lane >> 4;
  for (int kt = 0; kt < 16; ++kt) {
    // outstanding: tiles kt, kt+1 (8 loads) -> retire kt, keep kt+1 in flight
    if (kt < 15) asm volatile("s_waitcnt vmcnt(4)" ::: "memory");
    else         asm volatile("s_waitcnt vmcnt(0)" ::: "memory");
    asm volatile("s_barrier" ::: "memory");
    // stage kt+2 into slot (kt+2)%3 = (kt-1)%3: its readers finished compute
    // at kt-1, separated from this write by the barrier above (R5 argument).
    if (kt <= 13) {
      stageS<HW>(As[(kt + 2) % 3], pa + (kt + 2) * 32, t);
      stageS<HW>(Bs[(kt + 2) % 3], pb + (kt + 2) * 32, t);
    }
    const u16* Ac = As[kt % 3];
    const u16* Bc = Bs[kt % 3];
    short8 af[4], bf[4];
#pragma unroll
    for (int mi = 0; mi < 4; ++mi) {
      const int gr = wo * 64 + mi * 16 + (lane & 15);
      const int r = gr >> 1;
      const int p = ((gr & 1) * 4 + ks) ^ (r & 7);
      af[mi] = *(const short8*)(Ac + r * 64 + p * 8);
    }
#pragma unroll
    for (int ni = 0; ni < 4; ++ni) {
      const int gr = wn * 64 + ni * 16 + (lane & 15);
      const int r = gr >> 1;
      const int p = ((gr & 1) * 4 + ks) ^ (r & 7);
      bf[ni] = *(const short8*)(Bc + r * 64 + p * 8);
    }
#pragma unroll
    for (int ni = 0; ni < 4; ++ni)
#pragma unroll
      for (int mi = 0; mi < 4; ++mi)
        acc[ni][mi] = mfma_bf16(bf[ni], af[mi], acc[ni][mi]);
  }
  float* dst = part + ((size_t)(b * 6 + pair) * NS + ns) * 16384;
#pragma unroll
  for (int ni = 0; ni < 4; ++ni)
#pragma unroll
    for (int mi = 0; mi < 4; ++mi) {
      const int ai = wo * 64 + mi * 16 + (lane & 15);
      const int bj = wn * 64 + ni * 16 + ((lane >> 4) << 2);
      *(f32x4*)(dst + (size_t)ai * 128 + bj) = acc[ni][mi];
    }
}

// ---- reduce partials -> Goff bf16 (diag zeroed, mirrored) + Gd f32 ----------
__global__ __launch_bounds__(256) void k_greduce(const float* __restrict__ part,
                                                 u16* __restrict__ Goff,
                                                 float* __restrict__ Gd) {
  const int cq = blockIdx.x, pair = blockIdx.y, b = blockIdx.z;
  const int i = pair < 3 ? 0 : (pair < 5 ? 1 : 2);
  const int j = pair < 3 ? pair : (pair < 5 ? pair - 2 : 2);
  const int t = threadIdx.x;
  const int c0 = cq * 32;
  __shared__ u16 tl[32][136];
  const float* src = part + (size_t)(b * 6 + pair) * NS * 16384;
#pragma unroll
  for (int p = 0; p < 4; ++p) {
    const int q = t + p * 256;
    const int ai = q >> 3;
    const int bj = c0 + (q & 7) * 4;
    f32x4 s = zero4();
    for (int ns = 0; ns < NS; ++ns) s += *(const f32x4*)(src + (size_t)ns * 16384 + ai * 128 + bj);
    if (i == j) {
#pragma unroll
      for (int jj = 0; jj < 4; ++jj)
        if (ai == bj + jj) { Gd[b * CH + i * 128 + ai] = s[jj]; s[jj] = 0.f; }
    }
    u16x4 pk;
#pragma unroll
    for (int jj = 0; jj < 4; ++jj) { pk[jj] = f2bf(s[jj]); tl[bj - c0 + jj][ai] = pk[jj]; }
    *(u16x4*)(Goff + ((size_t)b * CH + i * 128 + ai) * CH + j * 128 + bj) = pk;
  }
  if (i != j) {
    __syncthreads();
#pragma unroll
    for (int jj = 0; jj < 2; ++jj) {
      const int r = t >> 3;
      const int ch = ((t & 7) + jj * 8) * 8;
      short8 v = *(const short8*)(&tl[r][ch]);
      *(short8*)(Goff + ((size_t)b * CH + j * 128 + c0 + r) * CH + i * 128 + ch) = v;
    }
  }
}

// ---- mini GEMM 128x128, K=384: C = A x B^T (B rows k-contig), ring-4 --------
// TM=1: T = Wqk*Goff + diagfix (f32 out).  TM=0: P = M*WvT (bf16 out).
template <int TM>
__global__ __launch_bounds__(256) void k_mini(const u16* __restrict__ A,
                                              const u16* __restrict__ B,
                                              float* __restrict__ Tout,
                                              u16* __restrict__ Bout,
                                              const float* __restrict__ Gd,
                                              const u16* __restrict__ Wd) {
  const int nt = blockIdx.x, mt = blockIdx.y, b = blockIdx.z;
  __shared__ u16 Ws[4][64 * 64];
  __shared__ u16 Xs[4][64 * 64];
  const int t = threadIdx.x, lane = t & 63, w = t >> 6;
  const int wo = w & 1, wn = w >> 1;
  const u16* Ab = A + (TM ? 0 : (size_t)b * CH * CH) + (size_t)mt * 128 * CH;
  const u16* Bb = B + (TM ? (size_t)b * CH * CH : 0) + (size_t)nt * 128 * CH;

  f32x4 acc[4][4];
#pragma unroll
  for (int a = 0; a < 4; ++a)
#pragma unroll
    for (int c = 0; c < 4; ++c) acc[a][c] = zero4();

#pragma unroll
  for (int p = 0; p < 3; ++p) {
    stageS<CH>(Ws[p], Ab + p * 32, t);
    stageS<CH>(Xs[p], Bb + p * 32, t);
  }
  const int ks = lane >> 4;
  for (int kt = 0; kt < 12; ++kt) {
    if (kt <= 9)       asm volatile("s_waitcnt vmcnt(8)" ::: "memory");
    else if (kt == 10) asm volatile("s_waitcnt vmcnt(4)" ::: "memory");
    else               asm volatile("s_waitcnt vmcnt(0)" ::: "memory");
    asm volatile("s_barrier" ::: "memory");
    if (kt < 9) {
      stageS<CH>(Ws[(kt + 3) & 3], Ab + (kt + 3) * 32, t);
      stageS<CH>(Xs[(kt + 3) & 3], Bb + (kt + 3) * 32, t);
    }
    const u16* Wc = Ws[kt & 3];
    const u16* Xc = Xs[kt & 3];
    short8 af[4], bfr[4];
#pragma unroll
    for (int mi = 0; mi < 4; ++mi) {
      const int gr = wo * 64 + mi * 16 + (lane & 15);
      const int r = gr >> 1;
      const int p = ((gr & 1) * 4 + ks) ^ (r & 7);
      af[mi] = *(const short8*)(Wc + r * 64 + p * 8);
    }
#pragma unroll
    for (int ni = 0; ni < 4; ++ni) {
      const int gr = wn * 64 + ni * 16 + (lane & 15);
      const int r = gr >> 1;
      const int p = ((gr & 1) * 4 + ks) ^ (r & 7);
      bfr[ni] = *(const short8*)(Xc + r * 64 + p * 8);
    }
#pragma unroll
    for (int ni = 0; ni < 4; ++ni)
#pragma unroll
      for (int mi = 0; mi < 4; ++mi)
        acc[ni][mi] = mfma_bf16(bfr[ni], af[mi], acc[ni][mi]);
  }

#pragma unroll
  for (int ni = 0; ni < 4; ++ni)
#pragma unroll
    for (int mi = 0; mi < 4; ++mi) {
      const int tr = mt * 128 + wo * 64 + mi * 16 + (lane & 15);   // A-row (C col)
      const int d0 = nt * 128 + wn * 64 + ni * 16 + ((lane >> 4) << 2);  // B-row
      if (TM) {
        f32x4 g = *(const f32x4*)(Gd + b * CH + d0);
        u16x4 w4 = *(const u16x4*)(Wd + (size_t)tr * CH + d0);
        f32x4 v;
#pragma unroll
        for (int jj = 0; jj < 4; ++jj) v[jj] = acc[ni][mi][jj] + bf2f(w4[jj]) * g[jj];
        *(f32x4*)(Tout + ((size_t)b * 768 + tr) * CH + d0) = v;
      } else {
        u16x4 pk;
#pragma unroll
        for (int jj = 0; jj < 4; ++jj) pk[jj] = f2bf(acc[ni][mi][jj]);
        *(u16x4*)(Bout + ((size_t)b * CH + tr) * CH + d0) = pk;
      }
    }
}

// ---- per (b,h): S = T1*Wk^T (MFMA, wave0) ; norms ; softmax ; M = proj∘attn -
__global__ __launch_bounds__(384) void k_attn(const float* __restrict__ T,
                                              const u16* __restrict__ wbf,
                                              const float* __restrict__ projw,
                                              const float* __restrict__ temp,
                                              u16* __restrict__ Mbf) {
  const int h = blockIdx.x, b = blockIdx.y, t = threadIdx.x;
  __shared__ float Sl[48][48];
  __shared__ float attn[48][48];
  __shared__ float nrm[96];
  const float* T1 = T + ((size_t)b * 768 + h * 48) * CH;
  const float* T2 = T1 + (size_t)384 * CH;
  const u16* wk = wbf + (size_t)(384 + h * 48) * CH;

  if (t < 64) {  // wave 0: S[48][48] via MFMA, K=384
    const int lane = t;
    f32x4 sa[3][3];
#pragma unroll
    for (int a = 0; a < 3; ++a)
#pragma unroll
      for (int c = 0; c < 3; ++c) sa[a][c] = zero4();
    for (int kk = 0; kk < 12; ++kk) {
      const int kc = kk * 32 + ((lane >> 4) << 3);
      short8 afr[3], bfr[3];
#pragma unroll
      for (int mi = 0; mi < 3; ++mi) {
        const float* s = T1 + (size_t)(mi * 16 + (lane & 15)) * CH + kc;
        f32x4 v0 = *(const f32x4*)(s);
        f32x4 v1 = *(const f32x4*)(s + 4);
        short8 a;
#pragma unroll
        for (int jj = 0; jj < 4; ++jj) { a[jj] = (short)f2bf(v0[jj]); a[4 + jj] = (short)f2bf(v1[jj]); }
        afr[mi] = a;
      }
#pragma unroll
      for (int ni = 0; ni < 3; ++ni)
        bfr[ni] = *(const short8*)(wk + (size_t)(ni * 16 + (lane & 15)) * CH + kc);
#pragma unroll
      for (int ni = 0; ni < 3; ++ni)
#pragma unroll
        for (int mi = 0; mi < 3; ++mi)
          sa[ni][mi] = mfma_bf16(bfr[ni], afr[mi], sa[ni][mi]);
    }
#pragma unroll
    for (int ni = 0; ni < 3; ++ni)
#pragma unroll
      for (int mi = 0; mi < 3; ++mi)
#pragma unroll
        for (int jj = 0; jj < 4; ++jj)
          Sl[mi * 16 + (lane & 15)][ni * 16 + ((lane >> 4) << 2) + jj] = sa[ni][mi][jj];
  } else if (t < 160) {  // norms, vectorized f32x4/u16x4
    const int r = t - 64;
    const float* Tr = (r < 48) ? T1 + (size_t)r * CH : T2 + (size_t)(r - 48) * CH;
    const u16* wr = (r < 48) ? wbf + (size_t)(h * 48 + r) * CH
                             : wbf + (size_t)(384 + h * 48 + (r - 48)) * CH;
    float a = 0.f;
    for (int c4 = 0; c4 < 96; ++c4) {
      f32x4 tv = *(const f32x4*)(Tr + c4 * 4);
      u16x4 wv = *(const u16x4*)(wr + c4 * 4);
#pragma unroll
      for (int jj = 0; jj < 4; ++jj) a = fmaf(tv[jj], bf2f(wv[jj]), a);
    }
    nrm[r] = a;
  }
  __syncthreads();
  if (t < 48) {
    const float th = temp[h];
    const float inq = 1.f / fmaxf(sqrtf(nrm[t]), 1e-12f);
    float l[48];
    float mx = -3.4e38f;
#pragma unroll
    for (int u = 0; u < 48; ++u) {
      float ik = 1.f / fmaxf(sqrtf(nrm[48 + u]), 1e-12f);
      float lg = Sl[t][u] * inq * ik * th;
      l[u] = lg;
      mx = fmaxf(mx, lg);
    }
    float sum = 0.f;
#pragma unroll
    for (int u = 0; u < 48; ++u) { float e = __expf(l[u] - mx); l[u] = e; sum += e; }
    float inv = 1.f / sum;
#pragma unroll
    for (int u = 0; u < 48; ++u) attn[t][u] = l[u] * inv;
  }
  __syncthreads();
  float pw[48];
#pragma unroll
  for (int c = 0; c < 48; ++c) pw[c] = projw[(size_t)t * CH + h * 48 + c];
  u16* Mb = Mbf + ((size_t)b * CH + t) * CH + h * 48;
#pragma unroll 4
  for (int d = 0; d < 48; ++d) {
    float a = 0.f;
#pragma unroll
    for (int c = 0; c < 48; ++c) a = fmaf(pw[c], attn[c][d], a);
    Mb[d] = f2bf(a);
  }
}

// ---- final: out[b] = P_b * xT  (R6 MODE-1 clone, ring-4, XCD swizzle) -------
__global__ __launch_bounds__(256) void k_final(const u16* __restrict__ P,
                                               const u16* __restrict__ Bx,
                                               float* __restrict__ outp) {
  constexpr int NWG = 3 * 128 * 4;
  constexpr int CHUNK = NWG / 8;
  const int orig = blockIdx.x;
  const int L = (orig & 7) * CHUNK + (orig >> 3);
  const int ot = L % 3;
  const int ntg = L / 3;
  const int b = ntg >> 7;
  const int nt = ntg & 127;

  __shared__ u16 Ws[4][64 * 64];
  __shared__ u16 Xs[4][64 * 64];
  const int t = threadIdx.x, lane = t & 63, w = t >> 6;
  const int wo = w & 1, wn = w >> 1;
  const u16* Ab = P + (size_t)b * CH * CH + (size_t)ot * 128 * CH;
  const u16* Bb = Bx + (size_t)b * HW * CH + (size_t)nt * 128 * CH;

  f32x4 acc[4][4];
#pragma unroll
  for (int a = 0; a < 4; ++a)
#pragma unroll
    for (int c = 0; c < 4; ++c) acc[a][c] = zero4();

#pragma unroll
  for (int p = 0; p < 3; ++p) {
    stageS<CH>(Ws[p], Ab + p * 32, t);
    stageS<CH>(Xs[p], Bb + p * 32, t);
  }
  const int ks = lane >> 4;
  for (int kt = 0; kt < 12; ++kt) {
    if (kt <= 9)       asm volatile("s_waitcnt vmcnt(8)" ::: "memory");
    else if (kt == 10) asm volatile("s_waitcnt vmcnt(4)" ::: "memory");
    else               asm volatile("s_waitcnt vmcnt(0)" ::: "memory");
    asm volatile("s_barrier" ::: "memory");
    if (kt < 9) {
      stageS<CH>(Ws[(kt + 3) & 3], Ab + (kt + 3) * 32, t);
      stageS<CH>(Xs[(kt + 3) & 3], Bb + (kt + 3) * 32, t);
    }
    const u16* Wc = Ws[kt & 3];
    const u16* Xc = Xs[kt & 3];
    short8 af[4], bfr[4];
#pragma unroll
    for (int mi = 0; mi < 4; ++mi) {
      const int gr = wo * 64 + mi * 16 + (lane & 15);
      const int r = gr >> 1;
      const int p = ((gr & 1) * 4 + ks) ^ (r & 7);
      af[mi] = *(const short8*)(Wc + r * 64 + p * 8);
    }
#pragma unroll
    for (int ni = 0; ni < 4; ++ni) {
      const int gr = wn * 64 + ni * 16 + (lane & 15);
      const int r = gr >> 1;
      const int p = ((gr & 1) * 4 + ks) ^ (r & 7);
      bfr[ni] = *(const short8*)(Xc + r * 64 + p * 8);
    }
#pragma unroll
    for (int ni = 0; ni < 4; ++ni)
#pragma unroll
      for (int mi = 0; mi < 4; ++mi)
        acc[ni][mi] = mfma_bf16(bfr[ni], af[mi], acc[ni][mi]);
  }
  float* ob = outp + (size_t)b * CH * HW;
#pragma unroll
  for (int ni = 0; ni < 4; ++ni)
#pragma unroll
    for (int mi = 0; mi < 4; ++mi) {
      int o = ot * 128 + wo * 64 + mi * 16 + (lane & 15);
      int n = nt * 128 + wn * 64 + ni * 16 + ((lane >> 4) << 2);
      *(f32x4*)(ob + (size_t)o * HW + n) = acc[ni][mi];
    }
}

extern "C" void kernel_launch(void* const* d_in, const int* in_sizes, int n_in,
                              void* d_out, int out_size, void* d_ws, size_t ws_size,
                              hipStream_t stream) {
  const float* x     = (const float*)d_in[0];
  const float* qkvw  = (const float*)d_in[1];
  const float* projw = (const float*)d_in[2];
  const float* temp  = (const float*)d_in[3];
  float* out = (float*)d_out;
  char* ws = (char*)d_ws;

  // ws layout
  u16*   xT   = (u16*)(ws);                      // 50,331,648
  u16*   wbf  = (u16*)(ws + 50331648);           // 884,736
  u16*   wvt  = (u16*)(ws + 51216384);           // 294,912
  u16*   Goff = (u16*)(ws + 51511296);           // 1,179,648
  float* Gd   = (float*)(ws + 52690944);         // 6,144
  float* Tf   = (float*)(ws + 52697088);         // 4,718,592
  u16*   Mbf  = (u16*)(ws + 57415680);           // 1,179,648
  u16*   Pbf  = (u16*)(ws + 58595328);           // 1,179,648
  // d_out scratch (dead before k_final writes): xb bf16 + gram partials
  u16*   xb   = (u16*)d_out;                     // 50,331,648
  float* part = (float*)((char*)d_out + 50331648);  // 6*NS*16384*4*4 = 50,331,648

  k_convert_w<<<dim3((1152 * CH + 255) / 256), 256, 0, stream>>>(qkvw, wbf);
  k_wvt<<<dim3(6, 6), 256, 0, stream>>>(qkvw, wvt);
  k_transpose_x<<<dim3(HW / 64, CH / 64, 4), 256, 0, stream>>>(x, xT, xb);
  k_gramx<<<dim3(6 * NS * 4), 256, 0, stream>>>(xb, part);
  k_greduce<<<dim3(4, 6, 4), 256, 0, stream>>>(part, Goff, Gd);
  k_mini<1><<<dim3(3, 6, 4), 256, 0, stream>>>(wbf, Goff, Tf, nullptr, Gd, wbf);
  k_attn<<<dim3(8, 4), 384, 0, stream>>>(Tf, wbf, projw, temp, Mbf);
  k_mini<0><<<dim3(3, 3, 4), 256, 0, stream>>>(Mbf, wvt, nullptr, Pbf, nullptr, nullptr);
  k_final<<<dim3(3 * 128 * 4), 256, 0, stream>>>(Pbf, xT, out);
}